// Round 14
// baseline (175.954 us; speedup 1.0000x reference)
//
#include <hip/hip_runtime.h>
#include <stdint.h>
#include <stddef.h>

typedef __attribute__((ext_vector_type(4))) int i32x4;

#define AS1q __attribute__((address_space(1)))
#define AS3q __attribute__((address_space(3)))

__device__ __forceinline__ void gload16(const void* g, void* l) {
    __builtin_amdgcn_global_load_lds((const AS1q uint32_t*)g, (AS3q uint32_t*)l, 16, 0, 0);
}

#define VMCNT4()  asm volatile("s_waitcnt vmcnt(4)" ::: "memory")
#define VMCNT0()  asm volatile("s_waitcnt vmcnt(0)" ::: "memory")
#define BARRIER() asm volatile("s_barrier" ::: "memory")
#define SB()      __builtin_amdgcn_sched_barrier(0)
#define SP1()     __builtin_amdgcn_s_setprio(1)
#define SP0()     __builtin_amdgcn_s_setprio(0)
#define MFMAI8(a, b, c) __builtin_amdgcn_mfma_i32_16x16x64_i8(a, b, c, 0, 0, 0)

#define EPSQ 1e-8f

// ---------------- Quant: one block per token (K == 4096 fast path) ----------------
__global__ __launch_bounds__(256) void quant4096(
    const float* __restrict__ x, int8_t* __restrict__ xq, float* __restrict__ sx)
{
    constexpr int K = 4096;
    const int t = blockIdx.x;
    const int tid = threadIdx.x;
    const float4* row4 = (const float4*)(x + (size_t)t * K);
    float4 v0 = row4[0 * 256 + tid];
    float4 v1 = row4[1 * 256 + tid];
    float4 v2 = row4[2 * 256 + tid];
    float4 v3 = row4[3 * 256 + tid];
    auto mx4 = [](float4 a) {
        return fmaxf(fmaxf(fabsf(a.x), fabsf(a.y)), fmaxf(fabsf(a.z), fabsf(a.w)));
    };
    float am = fmaxf(fmaxf(mx4(v0), mx4(v1)), fmaxf(mx4(v2), mx4(v3)));
    #pragma unroll
    for (int off = 32; off > 0; off >>= 1)
        am = fmaxf(am, __shfl_xor(am, off, 64));
    __shared__ float wmax[4];
    if ((tid & 63) == 0) wmax[tid >> 6] = am;
    __syncthreads();
    float r = fmaxf(fmaxf(wmax[0], wmax[1]), fmaxf(wmax[2], wmax[3]));
    const float s = fmaxf(r, EPSQ) / 127.0f;   // true fdiv: match reference
    if (tid == 0) sx[t] = s;
    int* qrow = (int*)(xq + (size_t)t * K);
    auto pack = [&](float4 a) {
        int q0 = (int)fminf(fmaxf(rintf(a.x / s), -128.f), 127.f);
        int q1 = (int)fminf(fmaxf(rintf(a.y / s), -128.f), 127.f);
        int q2 = (int)fminf(fmaxf(rintf(a.z / s), -128.f), 127.f);
        int q3 = (int)fminf(fmaxf(rintf(a.w / s), -128.f), 127.f);
        return (q0 & 255) | ((q1 & 255) << 8) | ((q2 & 255) << 16) | ((q3 & 255) << 24);
    };
    qrow[0 * 256 + tid] = pack(v0);
    qrow[1 * 256 + tid] = pack(v1);
    qrow[2 * 256 + tid] = pack(v2);
    qrow[3 * 256 + tid] = pack(v3);
}

// generic fallback (any K multiple of 4)
__global__ __launch_bounds__(256) void quant_any(
    const float* __restrict__ x, int8_t* __restrict__ xq, float* __restrict__ sx, int K)
{
    const int t = blockIdx.x;
    const int tid = threadIdx.x;
    const float* row = x + (size_t)t * K;
    float am = 0.f;
    for (int i = tid; i < K; i += 256) am = fmaxf(am, fabsf(row[i]));
    #pragma unroll
    for (int off = 32; off > 0; off >>= 1)
        am = fmaxf(am, __shfl_xor(am, off, 64));
    __shared__ float wmax[4];
    if ((tid & 63) == 0) wmax[tid >> 6] = am;
    __syncthreads();
    float r = fmaxf(fmaxf(wmax[0], wmax[1]), fmaxf(wmax[2], wmax[3]));
    const float s = fmaxf(r, EPSQ) / 127.0f;
    if (tid == 0) sx[t] = s;
    int8_t* qrow = xq + (size_t)t * K;
    for (int i = tid; i < K; i += 256) {
        float q = fminf(fmaxf(rintf(row[i] / s), -128.f), 127.f);
        qrow[i] = (int8_t)(int)q;
    }
}

// ---------------- Pack: weight arrives as int32 (harness ABI), repack to int8 ----------------
__global__ __launch_bounds__(256) void pack_w(
    const int* __restrict__ w32, int8_t* __restrict__ w8, long long n4)
{
    const long long stride = (long long)gridDim.x * 256;
    for (long long i = (long long)blockIdx.x * 256 + threadIdx.x; i < n4; i += stride) {
        int4 v = ((const int4*)w32)[i];
        ((int*)w8)[i] = (v.x & 255) | ((v.y & 255) << 8) | ((v.z & 255) << 16) | ((v.w & 255) << 24);
    }
}

// ---------------- int8 GEMM: R12 walled interleave + COUNTED vmcnt (T4) ----------------
// Geometry identical to R12: BM=256, BN=192, BK=128, 512 thr, 8 waves (2M x 4N),
// wave tile 128x48, R2-counter-verified swizzle, straight-line sched_barrier(0)
// walls with the proven read/MFMA group interleave (R12: 33->40% MfmaUtil).
// CHANGE (T4, m218): never drain vmcnt in the main loop. A: 3 buffers x 32KB
// (stage distance 2, full-tile flight ~2000cyc); B: 2 buffers x 24KB (distance
// 1, ~0.9-tile flight). LDS = 144KB -> 1 block/CU, 2 waves/SIMD.
// FIFO ledger (per tile: issue B(t+1) 3 loads, then A(t+2) 4 loads):
//   prologue: A0(4),B0(3),A1(4) out=11; top of each tile t: VMCNT4 retires
//   exactly {A(t),B(t)}, keeps A(t+1..) 4 in flight; barrier publishes.
//   Tail: tile NT-2 stages only B(NT-1); top of NT-1 = VMCNT0 (sole drain).
// Buffer safety: stage(t+1/t+2) overwrite buffers whose readers (tile t-1)
// all passed the top-of-tile-t barrier.
__global__ __launch_bounds__(512, 2) void gemm_i8(
    const int8_t* __restrict__ xq, const int8_t* __restrict__ w,
    const float* __restrict__ sx, const float* __restrict__ scale,
    const float* __restrict__ bias, float* __restrict__ out,
    int M, int N, int K)
{
    __shared__ __align__(16) uint8_t ldsA[3][32768];   // [buf][half 16KB x2]
    __shared__ __align__(16) uint8_t ldsB[2][24576];   // [buf][half 12KB x2]
    const int tid  = threadIdx.x;
    const int lane = tid & 63;
    const int wv   = tid >> 6;
    const int wr   = wv >> 2, wc = wv & 3;

    // bijective XCD swizzle (m204); nwg=512 -> %8==0
    const int nwg = gridDim.x;
    const int q8 = nwg >> 3, r8 = nwg & 7;
    const int xcd = blockIdx.x & 7, idx8 = blockIdx.x >> 3;
    const int wg = (xcd < r8 ? xcd * (q8 + 1) : r8 * (q8 + 1) + (xcd - r8) * q8) + idx8;

    const int NBM = M >> 8;
    const int bm = wg % NBM;
    const int bn = wg / NBM;             // col-panel-major: B panel (768KB) L2-resident
    const int brow = bm << 8, bcol = bn * 192;

    // staging sources (inverse-swizzled; R2/R12-verified formulas)
    const int8_t* srcA[4];
    #pragma unroll
    for (int e = 0; e < 4; ++e) {
        int half = e >> 1;
        int li = (e & 1) * 512 + tid;
        int R  = li >> 3;
        int xx = ((li & 7) << 4) ^ ((R & 7) << 4);
        srcA[e] = xq + (size_t)(brow + ((R << 1) | (xx >> 6))) * K + half * 64 + (xx & 63);
    }
    const int8_t* srcB[3];
    #pragma unroll
    for (int e = 0; e < 3; ++e) {
        int li = e * 512 + tid;
        int halfB = (li >= 768) ? 1 : 0;
        int lw = li - halfB * 768;
        int R  = lw >> 3;
        int xx = ((li & 7) << 4) ^ ((R & 7) << 4);
        srcB[e] = w + (size_t)(bcol + ((R << 1) | (xx >> 6))) * K + halfB * 64 + (xx & 63);
    }

    // fragment LDS byte offsets within a half-region (R2-verified formula)
    int offA[8], offB[3];
    #pragma unroll
    for (int m = 0; m < 8; ++m) {
        int r  = wr * 128 + m * 16 + (lane & 15);
        int R  = r >> 1;
        int x  = (((r & 1) << 6) | (lane & 48)) ^ ((R & 7) << 4);
        offA[m] = R * 128 + x;
    }
    #pragma unroll
    for (int n = 0; n < 3; ++n) {
        int r  = wc * 48 + n * 16 + (lane & 15);
        int R  = r >> 1;
        int x  = (((r & 1) << 6) | (lane & 48)) ^ ((R & 7) << 4);
        offB[n] = R * 128 + x;
    }

    i32x4 acc[8][3] = {};

#define STAGE_A(DST, TT) do { const size_t ko = (size_t)(TT) << 7;   \
        gload16(srcA[0] + ko, (DST) +         wv * 1024);            \
        gload16(srcA[1] + ko, (DST) +  8192 + wv * 1024);            \
        gload16(srcA[2] + ko, (DST) + 16384 + wv * 1024);            \
        gload16(srcA[3] + ko, (DST) + 24576 + wv * 1024); } while (0)
#define STAGE_B(DST, TT) do { const size_t ko = (size_t)(TT) << 7;   \
        gload16(srcB[0] + ko, (DST) +         wv * 1024);            \
        gload16(srcB[1] + ko, (DST) +  8192 + wv * 1024);            \
        gload16(srcB[2] + ko, (DST) + 16384 + wv * 1024); } while (0)

#define RA(BA, HH, V, MM) V = *(const i32x4*)((BA) + (HH) * 16384 + offA[MM])
#define RB(BB, HH, V, NN) V = *(const i32x4*)((BB) + (HH) * 12288 + offB[NN])

#define TILE_BODY(BA, BB) do {                                                \
        i32x4 a0,a1,a2,a3,a4,a5,a6,a7,b0,b1,b2;                               \
        i32x4 c0,c1,c2,c3,c4,c5,c6,c7,d0,d1,d2;                               \
        RA(BA,0,a0,0); RA(BA,0,a1,1); RB(BB,0,b0,0); RB(BB,0,b1,1); SB();     \
        RA(BA,0,a2,2); RA(BA,0,a3,3); RB(BB,0,b2,2); SB();                    \
        RA(BA,0,a4,4); RA(BA,0,a5,5); RA(BA,0,a6,6); RA(BA,0,a7,7); SB();     \
        SP1();                                                                \
        acc[0][0]=MFMAI8(a0,b0,acc[0][0]); acc[1][0]=MFMAI8(a1,b0,acc[1][0]); \
        acc[0][1]=MFMAI8(a0,b1,acc[0][1]); acc[1][1]=MFMAI8(a1,b1,acc[1][1]); \
        SP0(); SB();                                                          \
        RA(BA,1,c0,0); RA(BA,1,c1,1); RB(BB,1,d0,0); RB(BB,1,d1,1); SB();     \
        SP1();                                                                \
        acc[0][2]=MFMAI8(a0,b2,acc[0][2]); acc[1][2]=MFMAI8(a1,b2,acc[1][2]); \
        acc[2][0]=MFMAI8(a2,b0,acc[2][0]); acc[3][0]=MFMAI8(a3,b0,acc[3][0]); \
        acc[2][1]=MFMAI8(a2,b1,acc[2][1]); acc[3][1]=MFMAI8(a3,b1,acc[3][1]); \
        acc[2][2]=MFMAI8(a2,b2,acc[2][2]); acc[3][2]=MFMAI8(a3,b2,acc[3][2]); \
        SP0(); SB();                                                          \
        RA(BA,1,c2,2); RA(BA,1,c3,3); RB(BB,1,d2,2); SB();                    \
        SP1();                                                                \
        acc[4][0]=MFMAI8(a4,b0,acc[4][0]); acc[5][0]=MFMAI8(a5,b0,acc[5][0]); \
        acc[6][0]=MFMAI8(a6,b0,acc[6][0]); acc[7][0]=MFMAI8(a7,b0,acc[7][0]); \
        acc[4][1]=MFMAI8(a4,b1,acc[4][1]); acc[5][1]=MFMAI8(a5,b1,acc[5][1]); \
        acc[6][1]=MFMAI8(a6,b1,acc[6][1]); acc[7][1]=MFMAI8(a7,b1,acc[7][1]); \
        acc[4][2]=MFMAI8(a4,b2,acc[4][2]); acc[5][2]=MFMAI8(a5,b2,acc[5][2]); \
        acc[6][2]=MFMAI8(a6,b2,acc[6][2]); acc[7][2]=MFMAI8(a7,b2,acc[7][2]); \
        SP0(); SB();                                                          \
        RA(BA,1,c4,4); RA(BA,1,c5,5); RA(BA,1,c6,6); RA(BA,1,c7,7); SB();     \
        SP1();                                                                \
        acc[0][0]=MFMAI8(c0,d0,acc[0][0]); acc[1][0]=MFMAI8(c1,d0,acc[1][0]); \
        acc[0][1]=MFMAI8(c0,d1,acc[0][1]); acc[1][1]=MFMAI8(c1,d1,acc[1][1]); \
        acc[0][2]=MFMAI8(c0,d2,acc[0][2]); acc[1][2]=MFMAI8(c1,d2,acc[1][2]); \
        acc[2][0]=MFMAI8(c2,d0,acc[2][0]); acc[3][0]=MFMAI8(c3,d0,acc[3][0]); \
        acc[2][1]=MFMAI8(c2,d1,acc[2][1]); acc[3][1]=MFMAI8(c3,d1,acc[3][1]); \
        acc[2][2]=MFMAI8(c2,d2,acc[2][2]); acc[3][2]=MFMAI8(c3,d2,acc[3][2]); \
        acc[4][0]=MFMAI8(c4,d0,acc[4][0]); acc[5][0]=MFMAI8(c5,d0,acc[5][0]); \
        acc[6][0]=MFMAI8(c6,d0,acc[6][0]); acc[7][0]=MFMAI8(c7,d0,acc[7][0]); \
        acc[4][1]=MFMAI8(c4,d1,acc[4][1]); acc[5][1]=MFMAI8(c5,d1,acc[5][1]); \
        acc[6][1]=MFMAI8(c6,d1,acc[6][1]); acc[7][1]=MFMAI8(c7,d1,acc[7][1]); \
        acc[4][2]=MFMAI8(c4,d2,acc[4][2]); acc[5][2]=MFMAI8(c5,d2,acc[5][2]); \
        acc[6][2]=MFMAI8(c6,d2,acc[6][2]); acc[7][2]=MFMAI8(c7,d2,acc[7][2]); \
        SP0(); SB();                                                          \
    } while (0)

    const int NT = K >> 7;               // 32 for K=4096
    // prologue: A0, B0, A1 (FIFO: 4,3,4 = 11 out)
    STAGE_A(&ldsA[0][0], 0);
    STAGE_B(&ldsB[0][0], 0);
    STAGE_A(&ldsA[1][0], 1);

    int ia = 0;
    for (int t = 0; t < NT - 2; ++t) {
        uint8_t* bA = &ldsA[ia][0];
        uint8_t* bB = &ldsB[t & 1][0];
        int ia2 = ia + 2; if (ia2 >= 3) ia2 -= 3;
        VMCNT4(); BARRIER(); SB();       // retires {A(t),B(t)}; A(t+1) stays in flight
        STAGE_B(&ldsB[(t & 1) ^ 1][0], t + 1);
        STAGE_A(&ldsA[ia2][0], t + 2);
        SB();
        TILE_BODY(bA, bB);
        ia = (ia == 2) ? 0 : ia + 1;
    }
    {   // t = NT-2: stage only B(NT-1)
        uint8_t* bA = &ldsA[ia][0];
        uint8_t* bB = &ldsB[(NT - 2) & 1][0];
        VMCNT4(); BARRIER(); SB();
        STAGE_B(&ldsB[(NT - 1) & 1][0], NT - 1);
        SB();
        TILE_BODY(bA, bB);
        ia = (ia == 2) ? 0 : ia + 1;
    }
    {   // t = NT-1: sole drain
        uint8_t* bA = &ldsA[ia][0];
        uint8_t* bB = &ldsB[(NT - 1) & 1][0];
        VMCNT0(); BARRIER(); SB();
        TILE_BODY(bA, bB);
    }

    // epilogue: out = acc * sx[row] * scale[col] + bias[col]
    const int orow = brow + wr * 128;
    const int ocol = bcol + wc * 48;
    float sxv[8][4];
    #pragma unroll
    for (int m = 0; m < 8; ++m)
        #pragma unroll
        for (int j = 0; j < 4; ++j)
            sxv[m][j] = sx[orow + m * 16 + ((lane >> 4) << 2) + j];
    #pragma unroll
    for (int n = 0; n < 3; ++n) {
        const int col = ocol + n * 16 + (lane & 15);
        const float sc = scale[col];
        const float bi = bias[col];
        #pragma unroll
        for (int m = 0; m < 8; ++m) {
            const int rb = orow + m * 16 + ((lane >> 4) << 2);
            #pragma unroll
            for (int j = 0; j < 4; ++j)
                out[(size_t)(rb + j) * N + col] = (float)acc[m][n][j] * sxv[m][j] * sc + bi;
        }
    }
}

extern "C" void kernel_launch(void* const* d_in, const int* in_sizes, int n_in,
                              void* d_out, int out_size, void* d_ws, size_t ws_size,
                              hipStream_t stream) {
    const float* x     = (const float*)d_in[0];
    const int*   w32   = (const int*)d_in[1];     // int8 weight arrives as int32 (harness ABI)
    const float* scale = (const float*)d_in[2];
    const float* bias  = (const float*)d_in[3];
    float* out = (float*)d_out;

    const int N = in_sizes[2];           // 6144
    const int K = in_sizes[1] / N;       // 4096
    const int M = in_sizes[0] / K;       // 4096

    // ws layout: xq [M*K int8] | wq [N*K int8] | sx [M f32]
    int8_t* xqbuf = (int8_t*)d_ws;
    int8_t* wqbuf = (int8_t*)d_ws + (size_t)M * K;
    float*  sxbuf = (float*)((uint8_t*)d_ws + (size_t)M * K + (size_t)N * K);

    if (K == 4096)
        quant4096<<<M, 256, 0, stream>>>(x, xqbuf, sxbuf);
    else
        quant_any<<<M, 256, 0, stream>>>(x, xqbuf, sxbuf, K);

    pack_w<<<2048, 256, 0, stream>>>(w32, wqbuf, (long long)N * K / 4);

    const int nwg = (M / 256) * (N / 192);   // 16*32 = 512
    gemm_i8<<<nwg, 512, 0, stream>>>(xqbuf, wqbuf, sxbuf, scale, bias, out, M, N, K);
}

// Round 16
// 163.366 us; speedup vs baseline: 1.0771x; 1.0771x over previous
//
#include <hip/hip_runtime.h>
#include <stdint.h>
#include <stddef.h>

typedef __attribute__((ext_vector_type(4))) int i32x4;

#define AS1q __attribute__((address_space(1)))
#define AS3q __attribute__((address_space(3)))

__device__ __forceinline__ void gload16(const void* g, void* l) {
    __builtin_amdgcn_global_load_lds((const AS1q uint32_t*)g, (AS3q uint32_t*)l, 16, 0, 0);
}

#define VMCNT4()  asm volatile("s_waitcnt vmcnt(4)" ::: "memory")
#define VMCNT0()  asm volatile("s_waitcnt vmcnt(0)" ::: "memory")
#define BARRIER() asm volatile("s_barrier" ::: "memory")
#define SB()      __builtin_amdgcn_sched_barrier(0)
#define SP1()     __builtin_amdgcn_s_setprio(1)
#define SP0()     __builtin_amdgcn_s_setprio(0)
#define MFMAI8(a, b, c) __builtin_amdgcn_mfma_i32_16x16x64_i8(a, b, c, 0, 0, 0)

#define EPSQ 1e-8f

// ---------------- Quant: one block per token (K == 4096 fast path) ----------------
__global__ __launch_bounds__(256) void quant4096(
    const float* __restrict__ x, int8_t* __restrict__ xq, float* __restrict__ sx)
{
    constexpr int K = 4096;
    const int t = blockIdx.x;
    const int tid = threadIdx.x;
    const float4* row4 = (const float4*)(x + (size_t)t * K);
    float4 v0 = row4[0 * 256 + tid];
    float4 v1 = row4[1 * 256 + tid];
    float4 v2 = row4[2 * 256 + tid];
    float4 v3 = row4[3 * 256 + tid];
    auto mx4 = [](float4 a) {
        return fmaxf(fmaxf(fabsf(a.x), fabsf(a.y)), fmaxf(fabsf(a.z), fabsf(a.w)));
    };
    float am = fmaxf(fmaxf(mx4(v0), mx4(v1)), fmaxf(mx4(v2), mx4(v3)));
    #pragma unroll
    for (int off = 32; off > 0; off >>= 1)
        am = fmaxf(am, __shfl_xor(am, off, 64));
    __shared__ float wmax[4];
    if ((tid & 63) == 0) wmax[tid >> 6] = am;
    __syncthreads();
    float r = fmaxf(fmaxf(wmax[0], wmax[1]), fmaxf(wmax[2], wmax[3]));
    const float s = fmaxf(r, EPSQ) / 127.0f;   // true fdiv: match reference
    if (tid == 0) sx[t] = s;
    int* qrow = (int*)(xq + (size_t)t * K);
    auto pack = [&](float4 a) {
        int q0 = (int)fminf(fmaxf(rintf(a.x / s), -128.f), 127.f);
        int q1 = (int)fminf(fmaxf(rintf(a.y / s), -128.f), 127.f);
        int q2 = (int)fminf(fmaxf(rintf(a.z / s), -128.f), 127.f);
        int q3 = (int)fminf(fmaxf(rintf(a.w / s), -128.f), 127.f);
        return (q0 & 255) | ((q1 & 255) << 8) | ((q2 & 255) << 16) | ((q3 & 255) << 24);
    };
    qrow[0 * 256 + tid] = pack(v0);
    qrow[1 * 256 + tid] = pack(v1);
    qrow[2 * 256 + tid] = pack(v2);
    qrow[3 * 256 + tid] = pack(v3);
}

// generic fallback (any K multiple of 4)
__global__ __launch_bounds__(256) void quant_any(
    const float* __restrict__ x, int8_t* __restrict__ xq, float* __restrict__ sx, int K)
{
    const int t = blockIdx.x;
    const int tid = threadIdx.x;
    const float* row = x + (size_t)t * K;
    float am = 0.f;
    for (int i = tid; i < K; i += 256) am = fmaxf(am, fabsf(row[i]));
    #pragma unroll
    for (int off = 32; off > 0; off >>= 1)
        am = fmaxf(am, __shfl_xor(am, off, 64));
    __shared__ float wmax[4];
    if ((tid & 63) == 0) wmax[tid >> 6] = am;
    __syncthreads();
    float r = fmaxf(fmaxf(wmax[0], wmax[1]), fmaxf(wmax[2], wmax[3]));
    const float s = fmaxf(r, EPSQ) / 127.0f;
    if (tid == 0) sx[t] = s;
    int8_t* qrow = xq + (size_t)t * K;
    for (int i = tid; i < K; i += 256) {
        float q = fminf(fmaxf(rintf(row[i] / s), -128.f), 127.f);
        qrow[i] = (int8_t)(int)q;
    }
}

// ---------------- Pack: weight arrives as int32 (harness ABI), repack to int8 ----------------
__global__ __launch_bounds__(256) void pack_w(
    const int* __restrict__ w32, int8_t* __restrict__ w8, long long n4)
{
    const long long stride = (long long)gridDim.x * 256;
    for (long long i = (long long)blockIdx.x * 256 + threadIdx.x; i < n4; i += stride) {
        int4 v = ((const int4*)w32)[i];
        ((int*)w8)[i] = (v.x & 255) | ((v.y & 255) << 8) | ((v.z & 255) << 16) | ((v.w & 255) << 24);
    }
}

// ---------------- int8 GEMM: R12 body + counted vmcnt, STATIC 3A/2B buffers ----------------
// Unconfounded T4 A/B vs R12: identical geometry (BM=256, BN=192, BK=128,
// 512 thr, 8 waves 2Mx4N, wave tile 128x48), identical tile body (read/MFMA
// group interleave, stage in MID-BODY after the 11 first-half reads), identical
// swizzle (R2 counter-verified). ONLY change: A 3 bufs / B 2 bufs + vmcnt(4)
// at tile top (keeps A(t+1)'s 4 loads in flight across the barrier), with the
// 6-tile period UNROLLED so all LDS bases are compile-time (R14's runtime
// indexing + top-of-tile stage were confounds; VGPR 112->96 showed codegen damage).
// Ledger: prologue A0,B0,A1 (11 out). Tile t top: vmcnt(4) retires {A(t),B(t)},
// keeps A(t+1); mid-body stages B(t+1) (flight ~0.5 tile) + A(t+2) (~1.5 tiles)
// -> 11 out again. Tile NT-2 stages only B(NT-1) (7 out); tile NT-1: vmcnt(0).
// Overwrite safety: stage targets were last read at tile t-1, fenced by the
// top-of-tile-t barrier. Requires (NT-2)%6==0 (K=4096 -> NT=32 ok).
__global__ __launch_bounds__(512, 2) void gemm_i8(
    const int8_t* __restrict__ xq, const int8_t* __restrict__ w,
    const float* __restrict__ sx, const float* __restrict__ scale,
    const float* __restrict__ bias, float* __restrict__ out,
    int M, int N, int K)
{
    __shared__ __align__(16) uint8_t ldsA[3][32768];   // [buf][half 16KB x2]
    __shared__ __align__(16) uint8_t ldsB[2][24576];   // [buf][half 12KB x2]
    const int tid  = threadIdx.x;
    const int lane = tid & 63;
    const int wv   = tid >> 6;
    const int wr   = wv >> 2, wc = wv & 3;

    // bijective XCD swizzle (m204); nwg=512 -> %8==0
    const int nwg = gridDim.x;
    const int q8 = nwg >> 3, r8 = nwg & 7;
    const int xcd = blockIdx.x & 7, idx8 = blockIdx.x >> 3;
    const int wg = (xcd < r8 ? xcd * (q8 + 1) : r8 * (q8 + 1) + (xcd - r8) * q8) + idx8;

    const int NBM = M >> 8;
    const int bm = wg % NBM;
    const int bn = wg / NBM;             // col-panel-major: B panel (768KB) L2-resident
    const int brow = bm << 8, bcol = bn * 192;

    // staging sources (inverse-swizzled; R2/R12-verified formulas)
    const int8_t* srcA[4];
    #pragma unroll
    for (int e = 0; e < 4; ++e) {
        int half = e >> 1;
        int li = (e & 1) * 512 + tid;
        int R  = li >> 3;
        int xx = ((li & 7) << 4) ^ ((R & 7) << 4);
        srcA[e] = xq + (size_t)(brow + ((R << 1) | (xx >> 6))) * K + half * 64 + (xx & 63);
    }
    const int8_t* srcB[3];
    #pragma unroll
    for (int e = 0; e < 3; ++e) {
        int li = e * 512 + tid;
        int halfB = (li >= 768) ? 1 : 0;
        int lw = li - halfB * 768;
        int R  = lw >> 3;
        int xx = ((li & 7) << 4) ^ ((R & 7) << 4);
        srcB[e] = w + (size_t)(bcol + ((R << 1) | (xx >> 6))) * K + halfB * 64 + (xx & 63);
    }

    // fragment LDS byte offsets within a half-region (R2-verified formula)
    int offA[8], offB[3];
    #pragma unroll
    for (int m = 0; m < 8; ++m) {
        int r  = wr * 128 + m * 16 + (lane & 15);
        int R  = r >> 1;
        int x  = (((r & 1) << 6) | (lane & 48)) ^ ((R & 7) << 4);
        offA[m] = R * 128 + x;
    }
    #pragma unroll
    for (int n = 0; n < 3; ++n) {
        int r  = wc * 48 + n * 16 + (lane & 15);
        int R  = r >> 1;
        int x  = (((r & 1) << 6) | (lane & 48)) ^ ((R & 7) << 4);
        offB[n] = R * 128 + x;
    }

    i32x4 acc[8][3] = {};

#define STAGE_A(DST, TT) do { const size_t ko = (size_t)(TT) << 7;   \
        gload16(srcA[0] + ko, (DST) +         wv * 1024);            \
        gload16(srcA[1] + ko, (DST) +  8192 + wv * 1024);            \
        gload16(srcA[2] + ko, (DST) + 16384 + wv * 1024);            \
        gload16(srcA[3] + ko, (DST) + 24576 + wv * 1024); } while (0)
#define STAGE_B(DST, TT) do { const size_t ko = (size_t)(TT) << 7;   \
        gload16(srcB[0] + ko, (DST) +         wv * 1024);            \
        gload16(srcB[1] + ko, (DST) +  8192 + wv * 1024);            \
        gload16(srcB[2] + ko, (DST) + 16384 + wv * 1024); } while (0)

#define RA(BA, HH, V, MM) V = *(const i32x4*)((BA) + (HH) * 16384 + offA[MM])
#define RB(BB, HH, V, NN) V = *(const i32x4*)((BB) + (HH) * 12288 + offB[NN])

// R12's exact tile body; WAITC at top, stage code (variadic) in R12's mid-body slot.
#define TILE(BA, BB, WAITC, ...) do {                                         \
        i32x4 a0,a1,a2,a3,a4,a5,a6,a7,b0,b1,b2;                               \
        i32x4 c0,c1,c2,c3,c4,c5,c6,c7,d0,d1,d2;                               \
        WAITC; BARRIER(); SB();                                               \
        RA(BA,0,a0,0); RA(BA,0,a1,1); RB(BB,0,b0,0); RB(BB,0,b1,1); SB();     \
        RA(BA,0,a2,2); RA(BA,0,a3,3); RB(BB,0,b2,2); SB();                    \
        RA(BA,0,a4,4); RA(BA,0,a5,5); RA(BA,0,a6,6); RA(BA,0,a7,7); SB();     \
        __VA_ARGS__;                                                          \
        SB();                                                                 \
        SP1();                                                                \
        acc[0][0]=MFMAI8(a0,b0,acc[0][0]); acc[1][0]=MFMAI8(a1,b0,acc[1][0]); \
        acc[0][1]=MFMAI8(a0,b1,acc[0][1]); acc[1][1]=MFMAI8(a1,b1,acc[1][1]); \
        SP0(); SB();                                                          \
        RA(BA,1,c0,0); RA(BA,1,c1,1); RB(BB,1,d0,0); RB(BB,1,d1,1); SB();     \
        SP1();                                                                \
        acc[0][2]=MFMAI8(a0,b2,acc[0][2]); acc[1][2]=MFMAI8(a1,b2,acc[1][2]); \
        acc[2][0]=MFMAI8(a2,b0,acc[2][0]); acc[3][0]=MFMAI8(a3,b0,acc[3][0]); \
        acc[2][1]=MFMAI8(a2,b1,acc[2][1]); acc[3][1]=MFMAI8(a3,b1,acc[3][1]); \
        acc[2][2]=MFMAI8(a2,b2,acc[2][2]); acc[3][2]=MFMAI8(a3,b2,acc[3][2]); \
        SP0(); SB();                                                          \
        RA(BA,1,c2,2); RA(BA,1,c3,3); RB(BB,1,d2,2); SB();                    \
        SP1();                                                                \
        acc[4][0]=MFMAI8(a4,b0,acc[4][0]); acc[5][0]=MFMAI8(a5,b0,acc[5][0]); \
        acc[6][0]=MFMAI8(a6,b0,acc[6][0]); acc[7][0]=MFMAI8(a7,b0,acc[7][0]); \
        acc[4][1]=MFMAI8(a4,b1,acc[4][1]); acc[5][1]=MFMAI8(a5,b1,acc[5][1]); \
        acc[6][1]=MFMAI8(a6,b1,acc[6][1]); acc[7][1]=MFMAI8(a7,b1,acc[7][1]); \
        acc[4][2]=MFMAI8(a4,b2,acc[4][2]); acc[5][2]=MFMAI8(a5,b2,acc[5][2]); \
        acc[6][2]=MFMAI8(a6,b2,acc[6][2]); acc[7][2]=MFMAI8(a7,b2,acc[7][2]); \
        SP0(); SB();                                                          \
        RA(BA,1,c4,4); RA(BA,1,c5,5); RA(BA,1,c6,6); RA(BA,1,c7,7); SB();     \
        SP1();                                                                \
        acc[0][0]=MFMAI8(c0,d0,acc[0][0]); acc[1][0]=MFMAI8(c1,d0,acc[1][0]); \
        acc[0][1]=MFMAI8(c0,d1,acc[0][1]); acc[1][1]=MFMAI8(c1,d1,acc[1][1]); \
        acc[0][2]=MFMAI8(c0,d2,acc[0][2]); acc[1][2]=MFMAI8(c1,d2,acc[1][2]); \
        acc[2][0]=MFMAI8(c2,d0,acc[2][0]); acc[3][0]=MFMAI8(c3,d0,acc[3][0]); \
        acc[2][1]=MFMAI8(c2,d1,acc[2][1]); acc[3][1]=MFMAI8(c3,d1,acc[3][1]); \
        acc[2][2]=MFMAI8(c2,d2,acc[2][2]); acc[3][2]=MFMAI8(c3,d2,acc[3][2]); \
        acc[4][0]=MFMAI8(c4,d0,acc[4][0]); acc[5][0]=MFMAI8(c5,d0,acc[5][0]); \
        acc[6][0]=MFMAI8(c6,d0,acc[6][0]); acc[7][0]=MFMAI8(c7,d0,acc[7][0]); \
        acc[4][1]=MFMAI8(c4,d1,acc[4][1]); acc[5][1]=MFMAI8(c5,d1,acc[5][1]); \
        acc[6][1]=MFMAI8(c6,d1,acc[6][1]); acc[7][1]=MFMAI8(c7,d1,acc[7][1]); \
        acc[4][2]=MFMAI8(c4,d2,acc[4][2]); acc[5][2]=MFMAI8(c5,d2,acc[5][2]); \
        acc[6][2]=MFMAI8(c6,d2,acc[6][2]); acc[7][2]=MFMAI8(c7,d2,acc[7][2]); \
        SP0(); SB();                                                          \
    } while (0)

    const int NT = K >> 7;               // 32 for K=4096; requires (NT-2)%6==0
    // prologue: A0, B0, A1 (FIFO: 4,3,4 = 11 out)
    STAGE_A(&ldsA[0][0], 0);
    STAGE_B(&ldsB[0][0], 0);
    STAGE_A(&ldsA[1][0], 1);

    for (int t = 0; t < NT - 2; t += 6) {
        TILE(&ldsA[0][0], &ldsB[0][0], VMCNT4(),
             STAGE_B(&ldsB[1][0], t + 1); STAGE_A(&ldsA[2][0], t + 2));
        TILE(&ldsA[1][0], &ldsB[1][0], VMCNT4(),
             STAGE_B(&ldsB[0][0], t + 2); STAGE_A(&ldsA[0][0], t + 3));
        TILE(&ldsA[2][0], &ldsB[0][0], VMCNT4(),
             STAGE_B(&ldsB[1][0], t + 3); STAGE_A(&ldsA[1][0], t + 4));
        TILE(&ldsA[0][0], &ldsB[1][0], VMCNT4(),
             STAGE_B(&ldsB[0][0], t + 4); STAGE_A(&ldsA[2][0], t + 5));
        TILE(&ldsA[1][0], &ldsB[0][0], VMCNT4(),
             STAGE_B(&ldsB[1][0], t + 5); STAGE_A(&ldsA[0][0], t + 6));
        TILE(&ldsA[2][0], &ldsB[1][0], VMCNT4(),
             STAGE_B(&ldsB[0][0], t + 6); STAGE_A(&ldsA[1][0], t + 7));
    }
    // tail: tiles NT-2 (=30: bufs A0,B0) and NT-1 (=31: bufs A1,B1)
    TILE(&ldsA[0][0], &ldsB[0][0], VMCNT4(),
         STAGE_B(&ldsB[1][0], NT - 1));
    TILE(&ldsA[1][0], &ldsB[1][0], VMCNT0(), );

    // epilogue: out = acc * sx[row] * scale[col] + bias[col]
    const int orow = brow + wr * 128;
    const int ocol = bcol + wc * 48;
    float sxv[8][4];
    #pragma unroll
    for (int m = 0; m < 8; ++m)
        #pragma unroll
        for (int j = 0; j < 4; ++j)
            sxv[m][j] = sx[orow + m * 16 + ((lane >> 4) << 2) + j];
    #pragma unroll
    for (int n = 0; n < 3; ++n) {
        const int col = ocol + n * 16 + (lane & 15);
        const float sc = scale[col];
        const float bi = bias[col];
        #pragma unroll
        for (int m = 0; m < 8; ++m) {
            const int rb = orow + m * 16 + ((lane >> 4) << 2);
            #pragma unroll
            for (int j = 0; j < 4; ++j)
                out[(size_t)(rb + j) * N + col] = (float)acc[m][n][j] * sxv[m][j] * sc + bi;
        }
    }
}

extern "C" void kernel_launch(void* const* d_in, const int* in_sizes, int n_in,
                              void* d_out, int out_size, void* d_ws, size_t ws_size,
                              hipStream_t stream) {
    const float* x     = (const float*)d_in[0];
    const int*   w32   = (const int*)d_in[1];     // int8 weight arrives as int32 (harness ABI)
    const float* scale = (const float*)d_in[2];
    const float* bias  = (const float*)d_in[3];
    float* out = (float*)d_out;

    const int N = in_sizes[2];           // 6144
    const int K = in_sizes[1] / N;       // 4096
    const int M = in_sizes[0] / K;       // 4096

    // ws layout: xq [M*K int8] | wq [N*K int8] | sx [M f32]
    int8_t* xqbuf = (int8_t*)d_ws;
    int8_t* wqbuf = (int8_t*)d_ws + (size_t)M * K;
    float*  sxbuf = (float*)((uint8_t*)d_ws + (size_t)M * K + (size_t)N * K);

    if (K == 4096)
        quant4096<<<M, 256, 0, stream>>>(x, xqbuf, sxbuf);
    else
        quant_any<<<M, 256, 0, stream>>>(x, xqbuf, sxbuf, K);

    pack_w<<<2048, 256, 0, stream>>>(w32, wqbuf, (long long)N * K / 4);

    const int nwg = (M / 256) * (N / 192);   // 16*32 = 512
    gemm_i8<<<nwg, 512, 0, stream>>>(xqbuf, wqbuf, sxbuf, scale, bias, out, M, N, K);
}

// Round 17
// 142.020 us; speedup vs baseline: 1.2389x; 1.1503x over previous
//
#include <hip/hip_runtime.h>
#include <stdint.h>
#include <stddef.h>

typedef __attribute__((ext_vector_type(4))) int i32x4;

#define AS1q __attribute__((address_space(1)))
#define AS3q __attribute__((address_space(3)))

__device__ __forceinline__ void gload16(const void* g, void* l) {
    __builtin_amdgcn_global_load_lds((const AS1q uint32_t*)g, (AS3q uint32_t*)l, 16, 0, 0);
}

#define VMCNT0()  asm volatile("s_waitcnt vmcnt(0)" ::: "memory")
#define BARRIER() asm volatile("s_barrier" ::: "memory")
#define SB()      __builtin_amdgcn_sched_barrier(0)
#define SP1()     __builtin_amdgcn_s_setprio(1)
#define SP0()     __builtin_amdgcn_s_setprio(0)
#define MFMAI8(a, b, c) __builtin_amdgcn_mfma_i32_16x16x64_i8(a, b, c, 0, 0, 0)

#define EPSQ 1e-8f

// ---------------- Quant: one block per token (K == 4096 fast path) ----------------
__global__ __launch_bounds__(256) void quant4096(
    const float* __restrict__ x, int8_t* __restrict__ xq, float* __restrict__ sx)
{
    constexpr int K = 4096;
    const int t = blockIdx.x;
    const int tid = threadIdx.x;
    const float4* row4 = (const float4*)(x + (size_t)t * K);
    float4 v0 = row4[0 * 256 + tid];
    float4 v1 = row4[1 * 256 + tid];
    float4 v2 = row4[2 * 256 + tid];
    float4 v3 = row4[3 * 256 + tid];
    auto mx4 = [](float4 a) {
        return fmaxf(fmaxf(fabsf(a.x), fabsf(a.y)), fmaxf(fabsf(a.z), fabsf(a.w)));
    };
    float am = fmaxf(fmaxf(mx4(v0), mx4(v1)), fmaxf(mx4(v2), mx4(v3)));
    #pragma unroll
    for (int off = 32; off > 0; off >>= 1)
        am = fmaxf(am, __shfl_xor(am, off, 64));
    __shared__ float wmax[4];
    if ((tid & 63) == 0) wmax[tid >> 6] = am;
    __syncthreads();
    float r = fmaxf(fmaxf(wmax[0], wmax[1]), fmaxf(wmax[2], wmax[3]));
    const float s = fmaxf(r, EPSQ) / 127.0f;   // true fdiv: match reference
    if (tid == 0) sx[t] = s;
    int* qrow = (int*)(xq + (size_t)t * K);
    auto pack = [&](float4 a) {
        int q0 = (int)fminf(fmaxf(rintf(a.x / s), -128.f), 127.f);
        int q1 = (int)fminf(fmaxf(rintf(a.y / s), -128.f), 127.f);
        int q2 = (int)fminf(fmaxf(rintf(a.z / s), -128.f), 127.f);
        int q3 = (int)fminf(fmaxf(rintf(a.w / s), -128.f), 127.f);
        return (q0 & 255) | ((q1 & 255) << 8) | ((q2 & 255) << 16) | ((q3 & 255) << 24);
    };
    qrow[0 * 256 + tid] = pack(v0);
    qrow[1 * 256 + tid] = pack(v1);
    qrow[2 * 256 + tid] = pack(v2);
    qrow[3 * 256 + tid] = pack(v3);
}

// generic fallback (any K multiple of 4)
__global__ __launch_bounds__(256) void quant_any(
    const float* __restrict__ x, int8_t* __restrict__ xq, float* __restrict__ sx, int K)
{
    const int t = blockIdx.x;
    const int tid = threadIdx.x;
    const float* row = x + (size_t)t * K;
    float am = 0.f;
    for (int i = tid; i < K; i += 256) am = fmaxf(am, fabsf(row[i]));
    #pragma unroll
    for (int off = 32; off > 0; off >>= 1)
        am = fmaxf(am, __shfl_xor(am, off, 64));
    __shared__ float wmax[4];
    if ((tid & 63) == 0) wmax[tid >> 6] = am;
    __syncthreads();
    float r = fmaxf(fmaxf(wmax[0], wmax[1]), fmaxf(wmax[2], wmax[3]));
    const float s = fmaxf(r, EPSQ) / 127.0f;
    if (tid == 0) sx[t] = s;
    int8_t* qrow = xq + (size_t)t * K;
    for (int i = tid; i < K; i += 256) {
        float q = fminf(fmaxf(rintf(row[i] / s), -128.f), 127.f);
        qrow[i] = (int8_t)(int)q;
    }
}

// ---------------- Pack: weight arrives as int32 (harness ABI), repack to int8 ----------------
__global__ __launch_bounds__(256) void pack_w(
    const int* __restrict__ w32, int8_t* __restrict__ w8, long long n4)
{
    const long long stride = (long long)gridDim.x * 256;
    for (long long i = (long long)blockIdx.x * 256 + threadIdx.x; i < n4; i += stride) {
        int4 v = ((const int4*)w32)[i];
        ((int*)w8)[i] = (v.x & 255) | ((v.y & 255) << 8) | ((v.z & 255) << 16) | ((v.w & 255) << 24);
    }
}

// ---------------- int8 GEMM: branchless sched-walled group interleave (R12, best) ----------------
// BM=256, BN=192, BK=128 (full tile). 512 thr, 8 waves (2M x 4N), wave tile
// 128x48 = 8x3 frags 16x16x64, two 64B K-halves per tile -> 48 MFMA + 22
// ds_read_b128 + 7 gload16 per tile per wave-equivalent.
// Steady-state tile body is STRAIGHT-LINE (no branches) with sched_barrier(0)
// walls between groups: reads issue ahead, compiler inserts its own counted
// lgkmcnt between groups, MFMA groups run while later read-groups' data is
// still in flight. Measured: MfmaUtil 40%, gemm 109.5us (R12).
// LDS: 2 bufs x 56KB (A 32KB | B 24KB) = 112KB -> 1 block/CU, 2 waves/SIMD.
// One vmcnt(0)+barrier per tile: stage(t+1) issued a FULL tile (~4100cyc >>
// 900cyc HBM) before its wait -> drain costs ~nothing AND guarantees all LDS
// writes landed before the read burst (counted-vmcnt variants measured -22%
// and -35%: in-flight gload_lds writes collide with the ds_read burst).
// Buffer safety: stage(t+1) writes buf[t^1], whose readers (tile t-1) all
// passed the top-of-tile-t barrier.
// Swizzle: R2-counter-verified (SQ_LDS_BANK_CONFLICT==0) two-64B-logical-rows-
// per-128B-phys-row XOR x^=(R&7)<<4; linear gload_lds dest + inverse-swizzled
// per-lane global src (rule #21).
// Grid (M/256)*(N/192) = 16*32 = 512 = exactly 2 rounds/CU, zero tail waste.
__global__ __launch_bounds__(512, 2) void gemm_i8(
    const int8_t* __restrict__ xq, const int8_t* __restrict__ w,
    const float* __restrict__ sx, const float* __restrict__ scale,
    const float* __restrict__ bias, float* __restrict__ out,
    int M, int N, int K)
{
    __shared__ __align__(16) uint8_t lds[2][57344];   // [buf][A 32KB | B 24KB]
    const int tid  = threadIdx.x;
    const int lane = tid & 63;
    const int wv   = tid >> 6;
    const int wr   = wv >> 2, wc = wv & 3;

    // bijective XCD swizzle (m204); nwg=512 -> %8==0
    const int nwg = gridDim.x;
    const int q8 = nwg >> 3, r8 = nwg & 7;
    const int xcd = blockIdx.x & 7, idx8 = blockIdx.x >> 3;
    const int wg = (xcd < r8 ? xcd * (q8 + 1) : r8 * (q8 + 1) + (xcd - r8) * q8) + idx8;

    const int NBM = M >> 8;
    const int bm = wg % NBM;
    const int bn = wg / NBM;             // col-panel-major: B panel (768KB) L2-resident
    const int brow = bm << 8, bcol = bn * 192;

    // staging sources (inverse-swizzled; R2-verified formula).
    // A region: [half][128 phys rows][128B] x2 halves = 32KB; chunk li=(e&1)*512+tid.
    const int8_t* srcA[4];
    #pragma unroll
    for (int e = 0; e < 4; ++e) {
        int half = e >> 1;
        int li = (e & 1) * 512 + tid;
        int R  = li >> 3;
        int xx = ((li & 7) << 4) ^ ((R & 7) << 4);
        srcA[e] = xq + (size_t)(brow + ((R << 1) | (xx >> 6))) * K + half * 64 + (xx & 63);
    }
    // B region: [half][96 phys rows][128B] x2 = 24KB contiguous; chunk li=e*512+tid.
    const int8_t* srcB[3];
    #pragma unroll
    for (int e = 0; e < 3; ++e) {
        int li = e * 512 + tid;
        int halfB = (li >= 768) ? 1 : 0;
        int lw = li - halfB * 768;
        int R  = lw >> 3;
        int xx = ((li & 7) << 4) ^ ((R & 7) << 4);
        srcB[e] = w + (size_t)(bcol + ((R << 1) | (xx >> 6))) * K + halfB * 64 + (xx & 63);
    }

    // fragment LDS byte offsets within a half-region (R2-verified formula)
    int offA[8], offB[3];
    #pragma unroll
    for (int m = 0; m < 8; ++m) {
        int r  = wr * 128 + m * 16 + (lane & 15);
        int R  = r >> 1;
        int x  = (((r & 1) << 6) | (lane & 48)) ^ ((R & 7) << 4);
        offA[m] = R * 128 + x;
    }
    #pragma unroll
    for (int n = 0; n < 3; ++n) {
        int r  = wc * 48 + n * 16 + (lane & 15);
        int R  = r >> 1;
        int x  = (((r & 1) << 6) | (lane & 48)) ^ ((R & 7) << 4);
        offB[n] = R * 128 + x;
    }

    i32x4 acc[8][3] = {};

#define STAGE(NB, TT) do { const size_t ko = (size_t)(TT) << 7;      \
        gload16(srcA[0] + ko, &lds[NB][        wv * 1024]);          \
        gload16(srcA[1] + ko, &lds[NB][ 8192 + wv * 1024]);          \
        gload16(srcA[2] + ko, &lds[NB][16384 + wv * 1024]);          \
        gload16(srcA[3] + ko, &lds[NB][24576 + wv * 1024]);          \
        gload16(srcB[0] + ko, &lds[NB][32768 + wv * 1024]);          \
        gload16(srcB[1] + ko, &lds[NB][40960 + wv * 1024]);          \
        gload16(srcB[2] + ko, &lds[NB][49152 + wv * 1024]); } while (0)

#define RA(BUF, HH, V, MM) V = *(const i32x4*)(&lds[BUF][(HH) * 16384 + offA[MM]])
#define RB(BUF, HH, V, NN) V = *(const i32x4*)(&lds[BUF][32768 + (HH) * 12288 + offB[NN]])

#define TILE(BUF, TT, DOSTAGE) do {                                           \
        i32x4 a0,a1,a2,a3,a4,a5,a6,a7,b0,b1,b2;                               \
        i32x4 c0,c1,c2,c3,c4,c5,c6,c7,d0,d1,d2;                               \
        VMCNT0(); BARRIER(); SB();                                            \
        RA(BUF,0,a0,0); RA(BUF,0,a1,1); RB(BUF,0,b0,0); RB(BUF,0,b1,1); SB(); \
        RA(BUF,0,a2,2); RA(BUF,0,a3,3); RB(BUF,0,b2,2); SB();                 \
        RA(BUF,0,a4,4); RA(BUF,0,a5,5); RA(BUF,0,a6,6); RA(BUF,0,a7,7); SB(); \
        if (DOSTAGE) { STAGE(BUF ^ 1, (TT) + 1); }                            \
        SB();                                                                 \
        SP1();                                                                \
        acc[0][0]=MFMAI8(a0,b0,acc[0][0]); acc[1][0]=MFMAI8(a1,b0,acc[1][0]); \
        acc[0][1]=MFMAI8(a0,b1,acc[0][1]); acc[1][1]=MFMAI8(a1,b1,acc[1][1]); \
        SP0(); SB();                                                          \
        RA(BUF,1,c0,0); RA(BUF,1,c1,1); RB(BUF,1,d0,0); RB(BUF,1,d1,1); SB(); \
        SP1();                                                                \
        acc[0][2]=MFMAI8(a0,b2,acc[0][2]); acc[1][2]=MFMAI8(a1,b2,acc[1][2]); \
        acc[2][0]=MFMAI8(a2,b0,acc[2][0]); acc[3][0]=MFMAI8(a3,b0,acc[3][0]); \
        acc[2][1]=MFMAI8(a2,b1,acc[2][1]); acc[3][1]=MFMAI8(a3,b1,acc[3][1]); \
        acc[2][2]=MFMAI8(a2,b2,acc[2][2]); acc[3][2]=MFMAI8(a3,b2,acc[3][2]); \
        SP0(); SB();                                                          \
        RA(BUF,1,c2,2); RA(BUF,1,c3,3); RB(BUF,1,d2,2); SB();                 \
        SP1();                                                                \
        acc[4][0]=MFMAI8(a4,b0,acc[4][0]); acc[5][0]=MFMAI8(a5,b0,acc[5][0]); \
        acc[6][0]=MFMAI8(a6,b0,acc[6][0]); acc[7][0]=MFMAI8(a7,b0,acc[7][0]); \
        acc[4][1]=MFMAI8(a4,b1,acc[4][1]); acc[5][1]=MFMAI8(a5,b1,acc[5][1]); \
        acc[6][1]=MFMAI8(a6,b1,acc[6][1]); acc[7][1]=MFMAI8(a7,b1,acc[7][1]); \
        acc[4][2]=MFMAI8(a4,b2,acc[4][2]); acc[5][2]=MFMAI8(a5,b2,acc[5][2]); \
        acc[6][2]=MFMAI8(a6,b2,acc[6][2]); acc[7][2]=MFMAI8(a7,b2,acc[7][2]); \
        SP0(); SB();                                                          \
        RA(BUF,1,c4,4); RA(BUF,1,c5,5); RA(BUF,1,c6,6); RA(BUF,1,c7,7); SB(); \
        SP1();                                                                \
        acc[0][0]=MFMAI8(c0,d0,acc[0][0]); acc[1][0]=MFMAI8(c1,d0,acc[1][0]); \
        acc[0][1]=MFMAI8(c0,d1,acc[0][1]); acc[1][1]=MFMAI8(c1,d1,acc[1][1]); \
        acc[0][2]=MFMAI8(c0,d2,acc[0][2]); acc[1][2]=MFMAI8(c1,d2,acc[1][2]); \
        acc[2][0]=MFMAI8(c2,d0,acc[2][0]); acc[3][0]=MFMAI8(c3,d0,acc[3][0]); \
        acc[2][1]=MFMAI8(c2,d1,acc[2][1]); acc[3][1]=MFMAI8(c3,d1,acc[3][1]); \
        acc[2][2]=MFMAI8(c2,d2,acc[2][2]); acc[3][2]=MFMAI8(c3,d2,acc[3][2]); \
        acc[4][0]=MFMAI8(c4,d0,acc[4][0]); acc[5][0]=MFMAI8(c5,d0,acc[5][0]); \
        acc[6][0]=MFMAI8(c6,d0,acc[6][0]); acc[7][0]=MFMAI8(c7,d0,acc[7][0]); \
        acc[4][1]=MFMAI8(c4,d1,acc[4][1]); acc[5][1]=MFMAI8(c5,d1,acc[5][1]); \
        acc[6][1]=MFMAI8(c6,d1,acc[6][1]); acc[7][1]=MFMAI8(c7,d1,acc[7][1]); \
        acc[4][2]=MFMAI8(c4,d2,acc[4][2]); acc[5][2]=MFMAI8(c5,d2,acc[5][2]); \
        acc[6][2]=MFMAI8(c6,d2,acc[6][2]); acc[7][2]=MFMAI8(c7,d2,acc[7][2]); \
        SP0(); SB();                                                          \
    } while (0)

    const int NT = K >> 7;               // 32 for K=4096 (even)
    STAGE(0, 0);
    for (int t = 0; t < NT - 2; t += 2) {
        TILE(0, t,     true);
        TILE(1, t + 1, true);
    }
    TILE(0, NT - 2, true);               // stages tile NT-1 into buf 1
    TILE(1, NT - 1, false);

    // epilogue: out = acc * sx[row] * scale[col] + bias[col]
    const int orow = brow + wr * 128;
    const int ocol = bcol + wc * 48;
    float sxv[8][4];
    #pragma unroll
    for (int m = 0; m < 8; ++m)
        #pragma unroll
        for (int j = 0; j < 4; ++j)
            sxv[m][j] = sx[orow + m * 16 + ((lane >> 4) << 2) + j];
    #pragma unroll
    for (int n = 0; n < 3; ++n) {
        const int col = ocol + n * 16 + (lane & 15);
        const float sc = scale[col];
        const float bi = bias[col];
        #pragma unroll
        for (int m = 0; m < 8; ++m) {
            const int rb = orow + m * 16 + ((lane >> 4) << 2);
            #pragma unroll
            for (int j = 0; j < 4; ++j)
                out[(size_t)(rb + j) * N + col] = (float)acc[m][n][j] * sxv[m][j] * sc + bi;
        }
    }
}

extern "C" void kernel_launch(void* const* d_in, const int* in_sizes, int n_in,
                              void* d_out, int out_size, void* d_ws, size_t ws_size,
                              hipStream_t stream) {
    const float* x     = (const float*)d_in[0];
    const int*   w32   = (const int*)d_in[1];     // int8 weight arrives as int32 (harness ABI)
    const float* scale = (const float*)d_in[2];
    const float* bias  = (const float*)d_in[3];
    float* out = (float*)d_out;

    const int N = in_sizes[2];           // 6144
    const int K = in_sizes[1] / N;       // 4096
    const int M = in_sizes[0] / K;       // 4096

    // ws layout: xq [M*K int8] | wq [N*K int8] | sx [M f32]
    int8_t* xqbuf = (int8_t*)d_ws;
    int8_t* wqbuf = (int8_t*)d_ws + (size_t)M * K;
    float*  sxbuf = (float*)((uint8_t*)d_ws + (size_t)M * K + (size_t)N * K);

    if (K == 4096)
        quant4096<<<M, 256, 0, stream>>>(x, xqbuf, sxbuf);
    else
        quant_any<<<M, 256, 0, stream>>>(x, xqbuf, sxbuf, K);

    pack_w<<<2048, 256, 0, stream>>>(w32, wqbuf, (long long)N * K / 4);

    const int nwg = (M / 256) * (N / 192);   // 16*32 = 512
    gemm_i8<<<nwg, 512, 0, stream>>>(xqbuf, wqbuf, sxbuf, scale, bias, out, M, N, K);
}